// Round 2
// baseline (287.570 us; speedup 1.0000x reference)
//
#include <hip/hip_runtime.h>

typedef __bf16 bf16;
typedef short s16x8 __attribute__((ext_vector_type(8)));   // 8 bf16 bits for MFMA frags
typedef float f32x4 __attribute__((ext_vector_type(4)));

#define B_  4096
#define L_  50
#define D_  64
#define SX  136   // Xs row stride (bf16 elems): 128 + 8 pad
#define SH  72    // Hs/Fs row stride: 64 + 8 pad

// ws layout (bf16 elems): transposed MFMA weights Wt[n][k] = W[k][n], converted f32->bf16
#define OFF_W1T 0        // [64][128]
#define OFF_W2T 8192     // [64][64]
#define OFF_W3T 12288    // [64][64]
#define OFF_A1T 16384    // [64][128]
#define OFF_A2T 24576    // [64][64]
#define WT_TOTAL 28672

__device__ __forceinline__ unsigned short f2b(float f) {
    __bf16 h = (__bf16)f;                       // RNE f32->bf16
    return __builtin_bit_cast(unsigned short, h);
}

// One wave computes a 16-row x 64-col layer: O = act(A @ W + bias)
// A: LDS bf16, row stride sA elems, K = KT*32. Wt: global bf16 [64][K].
// Layouts (guide-verified): A[m=lane&15][k=quad*8+j]; B[k=quad*8+j][n=lane&15];
// D: col=lane&15, row=quad*4+reg.
template<int KT, bool RELU>
__device__ __forceinline__ void layer(const bf16* A0, int sA,
                                      const bf16* Wt, const float* bias,
                                      bf16* O0, int sO, int lane)
{
    const int m = lane & 15, quad = lane >> 4;
    f32x4 acc[4] = {};
#pragma unroll
    for (int kt = 0; kt < KT; ++kt) {
        s16x8 a = *(const s16x8*)(A0 + m * sA + kt * 32 + quad * 8);
#pragma unroll
        for (int nt = 0; nt < 4; ++nt) {
            s16x8 b = *(const s16x8*)(Wt + (nt * 16 + m) * (KT * 32) + kt * 32 + quad * 8);
            acc[nt] = __builtin_amdgcn_mfma_f32_16x16x32_bf16(a, b, acc[nt], 0, 0, 0);
        }
    }
#pragma unroll
    for (int nt = 0; nt < 4; ++nt) {
        int c = nt * 16 + m;
        float bv = bias[c];
#pragma unroll
        for (int r4 = 0; r4 < 4; ++r4) {
            float v = acc[nt][r4] + bv;
            if (RELU) v = fmaxf(v, 0.f);
            O0[(quad * 4 + r4) * sO + c] = (bf16)v;
        }
    }
}

// att1: A = concat(F[16x64], q broadcast row[64]) -> K=128. q identical for all rows of a block.
__device__ __forceinline__ void layer_cat(const bf16* F0, int sF, const bf16* q,
                                          const bf16* Wt, const float* bias,
                                          bf16* O0, int sO, int lane)
{
    const int m = lane & 15, quad = lane >> 4;
    f32x4 acc[4] = {};
#pragma unroll
    for (int kt = 0; kt < 4; ++kt) {
        s16x8 a;
        if (kt < 2) a = *(const s16x8*)(F0 + m * sF + kt * 32 + quad * 8);
        else        a = *(const s16x8*)(q + (kt - 2) * 32 + quad * 8); // row-independent broadcast
#pragma unroll
        for (int nt = 0; nt < 4; ++nt) {
            s16x8 b = *(const s16x8*)(Wt + (nt * 16 + m) * 128 + kt * 32 + quad * 8);
            acc[nt] = __builtin_amdgcn_mfma_f32_16x16x32_bf16(a, b, acc[nt], 0, 0, 0);
        }
    }
#pragma unroll
    for (int nt = 0; nt < 4; ++nt) {
        int c = nt * 16 + m;
        float bv = bias[c];
#pragma unroll
        for (int r4 = 0; r4 < 4; ++r4) {
            float v = fmaxf(acc[nt][r4] + bv, 0.f);
            O0[(quad * 4 + r4) * sO + c] = (bf16)v;
        }
    }
}

extern "C" __global__ void prep_weights(const float* __restrict__ w1, const float* __restrict__ w2,
                                        const float* __restrict__ w3, const float* __restrict__ a1,
                                        const float* __restrict__ a2, bf16* __restrict__ wt)
{
    int i = blockIdx.x * blockDim.x + threadIdx.x;
    if (i >= WT_TOTAL) return;
    const float* src; int off, K;
    if      (i < OFF_W2T) { src = w1; off = OFF_W1T; K = 128; }
    else if (i < OFF_W3T) { src = w2; off = OFF_W2T; K = 64;  }
    else if (i < OFF_A1T) { src = w3; off = OFF_W3T; K = 64;  }
    else if (i < OFF_A2T) { src = a1; off = OFF_A1T; K = 128; }
    else                  { src = a2; off = OFF_A2T; K = 64;  }
    int li = i - off;
    int n = li / K, k = li - n * K;
    wt[i] = (bf16)src[k * 64 + n];   // Wt[n][k] = W[k][n]
}

extern "C" __global__ void __launch_bounds__(256)
item_main(const int* __restrict__ nodes_v, const int* __restrict__ neigh_u,
          const int* __restrict__ neigh_r,
          const float* __restrict__ embed_u, const float* __restrict__ embed_i,
          const float* __restrict__ embed_r,
          const float* __restrict__ gv_b1, const float* __restrict__ gv_b2,
          const float* __restrict__ gv_b3,
          const float* __restrict__ att_b1, const float* __restrict__ att_b2,
          const float* __restrict__ att_w3, const float* __restrict__ att_b3,
          const float* __restrict__ wr1_w, const float* __restrict__ wr1_b,
          const float* __restrict__ wr2_w, const float* __restrict__ wr2_b,
          const bf16* __restrict__ wt, float* __restrict__ out)
{
    __shared__ __align__(16) bf16 Xs[64 * SX];
    __shared__ __align__(16) bf16 Hs[64 * SH];
    __shared__ __align__(16) bf16 Fs[64 * SH];
    __shared__ __align__(16) bf16 qb[64];      // bf16 copy of qj for att1 MFMA
    __shared__ float qbF[64];                  // f32 copy for epilogue
    __shared__ float muS[64];                  // softmax weights, reused as z
    __shared__ float zf[64];

    const int b = blockIdx.x;
    const int tid = threadIdx.x;
    const int lane = tid & 63, wave = tid >> 6;

    // ---- stage qj ----
    if (tid < 64) {
        int v = nodes_v[b];
        float qv = embed_i[v * 64 + tid];
        qbF[tid] = qv;
        qb[tid] = (bf16)qv;
    }
    // ---- gather pt|er (f32) -> Xs (bf16), rows >= L_ zeroed ----
    {
        const int rsub = tid >> 5;    // 8 rows per pass
        const int c = tid & 31;       // 32 float4 chunks per row (16 user + 16 rating)
#pragma unroll
        for (int it = 0; it < 8; ++it) {
            int row = it * 8 + rsub;
            float4 v = make_float4(0.f, 0.f, 0.f, 0.f);
            if (row < L_) {
                if (c < 16) {
                    int u = neigh_u[b * L_ + row];
                    v = *(const float4*)(embed_u + u * 64 + c * 4);
                } else {
                    int r = neigh_r[b * L_ + row];
                    v = *(const float4*)(embed_r + r * 64 + (c - 16) * 4);
                }
            }
            // dest cols: c<16 -> c*4 ; c>=16 -> 64+(c-16)*4 == c*4  (same expression)
            uint2 p;
            p.x = (unsigned)f2b(v.x) | ((unsigned)f2b(v.y) << 16);
            p.y = (unsigned)f2b(v.z) | ((unsigned)f2b(v.w) << 16);
            *(uint2*)(Xs + row * SX + c * 4) = p;
        }
    }
    __syncthreads();

    const bf16* w1t = wt + OFF_W1T;
    const bf16* w2t = wt + OFF_W2T;
    const bf16* w3t = wt + OFF_W3T;
    const bf16* a1t = wt + OFF_A1T;
    const bf16* a2t = wt + OFF_A2T;

    // Each wave owns rows [16w,16w+16): all 5 MFMA layers are row-local -> no barriers between.
    const int rb = wave * 16;
    layer<4, true >(Xs + rb * SX, SX, w1t, gv_b1, Hs + rb * SH, SH, lane); // gv1
    layer<2, true >(Hs + rb * SH, SH, w2t, gv_b2, Xs + rb * SX, SX, lane); // gv2 -> Xs[:,0:64]
    layer<2, false>(Xs + rb * SX, SX, w3t, gv_b3, Fs + rb * SH, SH, lane); // gv3 -> fjt
    layer_cat      (Fs + rb * SH, SH, qb, a1t, att_b1, Hs + rb * SH, SH, lane); // att1
    layer<2, true >(Hs + rb * SH, SH, a2t, att_b2, Xs + rb * SX, SX, lane);     // att2 -> Xs[:,0:64]
    __syncthreads();

    // ---- epilogue on wave 0 (all f32) ----
    if (wave == 0) {
        // scores[row] = att_b3 + a2[row] . att_w3
        float s = att_b3[0];
        {
            const int row = lane;
#pragma unroll
            for (int c = 0; c < 64; ++c)
                s += (float)Xs[row * SX + c] * att_w3[c];
        }
        if (lane >= L_) s = -1e30f;
        float mx = s;
#pragma unroll
        for (int off = 32; off; off >>= 1) mx = fmaxf(mx, __shfl_xor(mx, off));
        float e = (lane < L_) ? expf(s - mx) : 0.f;
        float sum = e;
#pragma unroll
        for (int off = 32; off; off >>= 1) sum += __shfl_xor(sum, off);
        muS[lane] = e / sum;

        // zj[d] = sum_l fjt[l][d] * mu[l]  (same-wave LDS RAW: DS pipe in-order)
        const int d = lane;
        float zj = 0.f;
        for (int l = 0; l < L_; ++l)
            zj += (float)Fs[l * SH + d] * muS[l];
        zf[d] = zj;

        // z = relu([zj|qj] @ wr1 + b1)   (f32 weights, coalesced column reads)
        float accz = wr1_b[d];
#pragma unroll 4
        for (int k = 0; k < 128; ++k) {
            float x = (k < 64) ? zf[k] : qbF[k - 64];
            accz = fmaf(wr1_w[k * 64 + d], x, accz);
        }
        accz = fmaxf(accz, 0.f);
        muS[d] = accz;  // reuse as z

        // out = relu(z @ wr2 + b2)
        float acco = wr2_b[d];
#pragma unroll 4
        for (int k = 0; k < 64; ++k)
            acco = fmaf(wr2_w[k * 64 + d], muS[k], acco);
        out[b * 64 + d] = fmaxf(acco, 0.f);
    }
}

extern "C" void kernel_launch(void* const* d_in, const int* in_sizes, int n_in,
                              void* d_out, int out_size, void* d_ws, size_t ws_size,
                              hipStream_t stream)
{
    const int* nodes_v = (const int*)d_in[0];
    const int* neigh_u = (const int*)d_in[1];
    const int* neigh_r = (const int*)d_in[2];
    const float* embed_u = (const float*)d_in[3];
    const float* embed_i = (const float*)d_in[4];
    const float* embed_r = (const float*)d_in[5];
    const float* gv_w1  = (const float*)d_in[6];  const float* gv_b1 = (const float*)d_in[7];
    const float* gv_w2  = (const float*)d_in[8];  const float* gv_b2 = (const float*)d_in[9];
    const float* gv_w3  = (const float*)d_in[10]; const float* gv_b3 = (const float*)d_in[11];
    const float* att_w1 = (const float*)d_in[12]; const float* att_b1 = (const float*)d_in[13];
    const float* att_w2 = (const float*)d_in[14]; const float* att_b2 = (const float*)d_in[15];
    const float* att_w3 = (const float*)d_in[16]; const float* att_b3 = (const float*)d_in[17];
    const float* wr1_w  = (const float*)d_in[18]; const float* wr1_b = (const float*)d_in[19];
    const float* wr2_w  = (const float*)d_in[20]; const float* wr2_b = (const float*)d_in[21];

    bf16* wt = (bf16*)d_ws;
    prep_weights<<<(WT_TOTAL + 255) / 256, 256, 0, stream>>>(gv_w1, gv_w2, gv_w3, att_w1, att_w2, wt);
    item_main<<<B_, 256, 0, stream>>>(nodes_v, neigh_u, neigh_r, embed_u, embed_i, embed_r,
                                      gv_b1, gv_b2, gv_b3, att_b1, att_b2, att_w3, att_b3,
                                      wr1_w, wr1_b, wr2_w, wr2_b, wt, (float*)d_out);
}

// Round 3
// 239.868 us; speedup vs baseline: 1.1989x; 1.1989x over previous
//
#include <hip/hip_runtime.h>

typedef __bf16 bf16;
typedef short s16x8 __attribute__((ext_vector_type(8)));   // 8 bf16 for MFMA frags
typedef float f32x4 __attribute__((ext_vector_type(4)));

#define B_   4096
#define L_   50
#define SX   136   // 128 + 8 pad (272B rows, 16B aligned)
#define SH   72    // 64 + 8 pad

// ws layout. bf16 elems:
#define OFF_W1T  0        // [64][128]  gv_w1^T
#define OFF_W2T  8192     // [64][64]   gv_w2^T
#define OFF_W3T  12288    // [64][64]   gv_w3^T
#define OFF_WCAT 16384    // [64][128]  [W3@A1_top ; A1_bot]^T
#define OFF_A2T  24576    // [64][64]   att_w2^T
#define OFF_R1T  28672    // [64][128]  wr1^T
#define OFF_R2T  36864    // [64][64]   wr2^T
#define WT_TOTAL 40960
#define BIAS1P_BYTE 81920 // float[64]  b3@A1_top + att_b1
#define ZQ_BYTE     82176 // bf16 [4096][128]  [zj | qj]

__device__ __forceinline__ unsigned short f2b(float f) {
    __bf16 h = (__bf16)f;
    return __builtin_bit_cast(unsigned short, h);
}
__device__ __forceinline__ unsigned pack2(float a, float b) {
    return (unsigned)f2b(a) | ((unsigned)f2b(b) << 16);
}

// O = act(A @ W + bias): 16 rows x 64 cols per wave. A in LDS (stride sA), Wt[n][k] global bf16.
// Layouts (HW-verified in round 2): A[m=lane&15][k=quad*8+j]; B[k=quad*8+j][n=lane&15];
// C/D: col=lane&15 (per 16-tile), row=quad*4+reg.
template<int KT, bool RELU>
__device__ __forceinline__ void layer(const bf16* A0, int sA,
                                      const bf16* __restrict__ Wt, const float* __restrict__ bias,
                                      bf16* O0, int sO, int lane)
{
    const int m = lane & 15, quad = lane >> 4;
    f32x4 acc[4] = {};
#pragma unroll
    for (int kt = 0; kt < KT; ++kt) {
        s16x8 a = *(const s16x8*)(A0 + m * sA + kt * 32 + quad * 8);
#pragma unroll
        for (int nt = 0; nt < 4; ++nt) {
            s16x8 b = *(const s16x8*)(Wt + (nt * 16 + m) * (KT * 32) + kt * 32 + quad * 8);
            acc[nt] = __builtin_amdgcn_mfma_f32_16x16x32_bf16(a, b, acc[nt], 0, 0, 0);
        }
    }
#pragma unroll
    for (int nt = 0; nt < 4; ++nt) {
        int c = nt * 16 + m;
        float bv = bias[c];
#pragma unroll
        for (int r4 = 0; r4 < 4; ++r4) {
            float v = acc[nt][r4] + bv;
            if (RELU) v = fmaxf(v, 0.f);
            O0[(quad * 4 + r4) * sO + c] = (bf16)v;
        }
    }
}

// ---------------- prep: transpose weights to bf16 Wt[n][k], build WCAT and bias1' ----------------
extern "C" __global__ void prep_weights(const float* __restrict__ w1, const float* __restrict__ w2,
                                        const float* __restrict__ w3, const float* __restrict__ a1,
                                        const float* __restrict__ a2, const float* __restrict__ r1,
                                        const float* __restrict__ r2, const float* __restrict__ gb3,
                                        const float* __restrict__ ab1,
                                        bf16* __restrict__ wt, float* __restrict__ bias1p)
{
    int i = blockIdx.x * blockDim.x + threadIdx.x;
    if (i >= WT_TOTAL + 64) return;
    if (i >= WT_TOTAL) {                       // bias1'[n] = ab1[n] + sum_t gb3[t]*a1[t][n]
        int n = i - WT_TOTAL;
        float s = ab1[n];
        for (int t = 0; t < 64; ++t) s += gb3[t] * a1[t * 64 + n];
        bias1p[n] = s;
        return;
    }
    float val;
    if (i < OFF_W2T)       { int li = i;            int n = li >> 7, k = li & 127; val = w1[k * 64 + n]; }
    else if (i < OFF_W3T)  { int li = i - OFF_W2T;  int n = li >> 6, k = li & 63;  val = w2[k * 64 + n]; }
    else if (i < OFF_WCAT) { int li = i - OFF_W3T;  int n = li >> 6, k = li & 63;  val = w3[k * 64 + n]; }
    else if (i < OFF_A2T)  {                        // WCAT[n][k]
        int li = i - OFF_WCAT; int n = li >> 7, k = li & 127;
        if (k >= 64) val = a1[k * 64 + n];          // A1_bot row (k-64 of q)
        else {                                      // (W3 @ A1_top)[k][n]
            float s = 0.f;
            for (int t = 0; t < 64; ++t) s += w3[k * 64 + t] * a1[t * 64 + n];
            val = s;
        }
    }
    else if (i < OFF_R1T)  { int li = i - OFF_A2T;  int n = li >> 6, k = li & 63;  val = a2[k * 64 + n]; }
    else if (i < OFF_R2T)  { int li = i - OFF_R1T;  int n = li >> 7, k = li & 127; val = r1[k * 64 + n]; }
    else                   { int li = i - OFF_R2T;  int n = li >> 6, k = li & 63;  val = r2[k * 64 + n]; }
    wt[i] = (bf16)val;
}

// ---------------- main: gather + 4 fused layers + scores + softmax + zj -> zq ----------------
extern "C" __global__ void __launch_bounds__(256, 4)
item_main(const int* __restrict__ nodes_v, const int* __restrict__ neigh_u,
          const int* __restrict__ neigh_r,
          const float* __restrict__ embed_u, const float* __restrict__ embed_i,
          const float* __restrict__ embed_r,
          const float* __restrict__ gv_b1, const float* __restrict__ gv_b2,
          const float* __restrict__ gv_b3,
          const float* __restrict__ att_b2, const float* __restrict__ att_w3,
          const float* __restrict__ att_b3,
          const bf16* __restrict__ wt, const float* __restrict__ bias1p,
          bf16* __restrict__ zq)
{
    __shared__ __align__(16) bf16 Xs[64 * SX];
    __shared__ __align__(16) bf16 Hs[64 * SH];
    __shared__ float scs[64];
    __shared__ float muS[64];
    __shared__ float zp[4 * 64];

    const int b = blockIdx.x;
    const int tid = threadIdx.x;
    const int lane = tid & 63, wave = tid >> 6;
    const int m = lane & 15, quad = lane >> 4;
    const int rb = wave * 16;
    const int v = nodes_v[b];

    // ---- q fragments (A-layout, rows broadcast): qf[t] = q[t*32 + quad*8 .. +8], regs only ----
    s16x8 qf[2];
#pragma unroll
    for (int t = 0; t < 2; ++t) {
        float4 qa = *(const float4*)(embed_i + v * 64 + t * 32 + quad * 8);
        float4 qb4 = *(const float4*)(embed_i + v * 64 + t * 32 + quad * 8 + 4);
        s16x8 r;
        r[0] = (short)f2b(qa.x); r[1] = (short)f2b(qa.y); r[2] = (short)f2b(qa.z); r[3] = (short)f2b(qa.w);
        r[4] = (short)f2b(qb4.x); r[5] = (short)f2b(qb4.y); r[6] = (short)f2b(qb4.z); r[7] = (short)f2b(qb4.w);
        qf[t] = r;
    }

    // ---- wave-local gather: wave w stages its own rows [rb, rb+16) -> no barrier before gv1 ----
    {
        const int rsub = lane >> 4;   // 4 rows per iter
        const int c = lane & 15;      // 16B chunk within 256B half-row
#pragma unroll
        for (int it = 0; it < 4; ++it) {
            int row = rb + it * 4 + rsub;
            float4 vu = make_float4(0.f, 0.f, 0.f, 0.f), vr = vu;
            if (row < L_) {
                int u = neigh_u[b * L_ + row];
                int r = neigh_r[b * L_ + row];
                vu = *(const float4*)(embed_u + u * 64 + c * 4);
                vr = *(const float4*)(embed_r + r * 64 + c * 4);
            }
            uint2 pu, pr;
            pu.x = pack2(vu.x, vu.y); pu.y = pack2(vu.z, vu.w);
            pr.x = pack2(vr.x, vr.y); pr.y = pack2(vr.z, vr.w);
            *(uint2*)(Xs + row * SX + c * 4) = pu;
            *(uint2*)(Xs + row * SX + 64 + c * 4) = pr;
        }
    }

    const bf16* w1t = wt + OFF_W1T;
    const bf16* w2t = wt + OFF_W2T;
    const bf16* w3t = wt + OFF_W3T;
    const bf16* wct = wt + OFF_WCAT;
    const bf16* a2t = wt + OFF_A2T;

    // gv1: X[0:128] -> H ; gv2: H -> X[0:64]   (row-local, no barriers)
    layer<4, true>(Xs + rb * SX, SX, w1t, gv_b1, Hs + rb * SH, SH, lane);
    layer<2, true>(Hs + rb * SH, SH, w2t, gv_b2, Xs + rb * SX, SX, lane);

    // fused gv3 + att1': both consume h2 = X[0:64]; fjt -> X[64:128], att1h -> H
    {
        f32x4 accF[4] = {}, accA[4] = {};
#pragma unroll
        for (int kt = 0; kt < 2; ++kt) {
            s16x8 a = *(const s16x8*)(Xs + (rb + m) * SX + kt * 32 + quad * 8);
#pragma unroll
            for (int nt = 0; nt < 4; ++nt) {
                s16x8 bf = *(const s16x8*)(w3t + (nt * 16 + m) * 64 + kt * 32 + quad * 8);
                s16x8 ba = *(const s16x8*)(wct + (nt * 16 + m) * 128 + kt * 32 + quad * 8);
                accF[nt] = __builtin_amdgcn_mfma_f32_16x16x32_bf16(a, bf, accF[nt], 0, 0, 0);
                accA[nt] = __builtin_amdgcn_mfma_f32_16x16x32_bf16(a, ba, accA[nt], 0, 0, 0);
            }
        }
#pragma unroll
        for (int kt = 2; kt < 4; ++kt) {
#pragma unroll
            for (int nt = 0; nt < 4; ++nt) {
                s16x8 ba = *(const s16x8*)(wct + (nt * 16 + m) * 128 + kt * 32 + quad * 8);
                accA[nt] = __builtin_amdgcn_mfma_f32_16x16x32_bf16(qf[kt - 2], ba, accA[nt], 0, 0, 0);
            }
        }
#pragma unroll
        for (int nt = 0; nt < 4; ++nt) {
            int c = nt * 16 + m;
            float b3v = gv_b3[c], b1v = bias1p[c];
#pragma unroll
            for (int r4 = 0; r4 < 4; ++r4) {
                int row = rb + quad * 4 + r4;
                Xs[row * SX + 64 + c] = (bf16)(accF[nt][r4] + b3v);          // fjt (no relu)
                Hs[row * SH + c] = (bf16)fmaxf(accA[nt][r4] + b1v, 0.f);     // att1h
            }
        }
    }

    // att2 in regs + fused relu + dot(att_w3) + quad-reduce -> scores (no LDS for a2)
    {
        f32x4 acc[4] = {};
#pragma unroll
        for (int kt = 0; kt < 2; ++kt) {
            s16x8 a = *(const s16x8*)(Hs + (rb + m) * SH + kt * 32 + quad * 8);
#pragma unroll
            for (int nt = 0; nt < 4; ++nt) {
                s16x8 bb = *(const s16x8*)(a2t + (nt * 16 + m) * 64 + kt * 32 + quad * 8);
                acc[nt] = __builtin_amdgcn_mfma_f32_16x16x32_bf16(a, bb, acc[nt], 0, 0, 0);
            }
        }
        float sc[4] = {0.f, 0.f, 0.f, 0.f};
#pragma unroll
        for (int nt = 0; nt < 4; ++nt) {
            int c = nt * 16 + m;
            float b2v = att_b2[c], w3v = att_w3[c];
#pragma unroll
            for (int r4 = 0; r4 < 4; ++r4)
                sc[r4] += fmaxf(acc[nt][r4] + b2v, 0.f) * w3v;
        }
#pragma unroll
        for (int mask = 1; mask < 16; mask <<= 1)
#pragma unroll
            for (int r4 = 0; r4 < 4; ++r4) sc[r4] += __shfl_xor(sc[r4], mask);
        if (m == 0) {
#pragma unroll
            for (int r4 = 0; r4 < 4; ++r4) scs[rb + quad * 4 + r4] = sc[r4];
        }
    }
    __syncthreads();   // scs + fjt visible to all

    // ---- softmax (wave 0) ----
    if (wave == 0) {
        float s = scs[lane] + att_b3[0];
        if (lane >= L_) s = -1e30f;
        float mx = s;
#pragma unroll
        for (int off = 32; off; off >>= 1) mx = fmaxf(mx, __shfl_xor(mx, off));
        float e = (lane < L_) ? __expf(s - mx) : 0.f;
        float sum = e;
#pragma unroll
        for (int off = 32; off; off >>= 1) sum += __shfl_xor(sum, off);
        muS[lane] = e / sum;
    }
    __syncthreads();

    // ---- zj partials: wave w handles l in [rb, rb+16) ----
    {
        float z = 0.f;
#pragma unroll
        for (int i = 0; i < 16; ++i) {
            int l = rb + i;
            z += (float)Xs[l * SX + 64 + lane] * muS[l];
        }
        zp[wave * 64 + lane] = z;
    }
    __syncthreads();

    if (wave == 0) {
        float z = zp[lane] + zp[64 + lane] + zp[128 + lane] + zp[192 + lane];
        zq[b * 128 + lane] = (bf16)z;
        zq[b * 128 + 64 + lane] = (bf16)embed_i[v * 64 + lane];
    }
}

// ---------------- combine: out = relu(relu(ZQ @ wr1 + b1) @ wr2 + b2), dense MFMA ----------------
extern "C" __global__ void __launch_bounds__(256, 4)
combine(const bf16* __restrict__ zq, const bf16* __restrict__ wt,
        const float* __restrict__ wr1_b, const float* __restrict__ wr2_b,
        float* __restrict__ out)
{
    __shared__ __align__(16) bf16 Zs[64 * SX];
    __shared__ __align__(16) bf16 Hs[64 * SH];
    const int tid = threadIdx.x;
    const int lane = tid & 63, wave = tid >> 6;
    const int m = lane & 15, quad = lane >> 4;
    const int b0 = blockIdx.x * 64;

    // stage 64 rows x 128 cols (coalesced 16B chunks)
#pragma unroll
    for (int it = 0; it < 4; ++it) {
        int idx = it * 256 + tid;           // 1024 chunks
        int row = idx >> 4, ch = idx & 15;
        *(uint4*)(Zs + row * SX + ch * 8) = *(const uint4*)(zq + b0 * 128 + idx * 8);
    }
    __syncthreads();

    const int rb = wave * 16;
    layer<4, true>(Zs + rb * SX, SX, wt + OFF_R1T, wr1_b, Hs + rb * SH, SH, lane);

    f32x4 acc[4] = {};
#pragma unroll
    for (int kt = 0; kt < 2; ++kt) {
        s16x8 a = *(const s16x8*)(Hs + (rb + m) * SH + kt * 32 + quad * 8);
#pragma unroll
        for (int nt = 0; nt < 4; ++nt) {
            s16x8 bb = *(const s16x8*)(wt + OFF_R2T + (nt * 16 + m) * 64 + kt * 32 + quad * 8);
            acc[nt] = __builtin_amdgcn_mfma_f32_16x16x32_bf16(a, bb, acc[nt], 0, 0, 0);
        }
    }
#pragma unroll
    for (int nt = 0; nt < 4; ++nt) {
        int c = nt * 16 + m;
        float bv = wr2_b[c];
#pragma unroll
        for (int r4 = 0; r4 < 4; ++r4) {
            int row = b0 + rb + quad * 4 + r4;
            out[row * 64 + c] = fmaxf(acc[nt][r4] + bv, 0.f);
        }
    }
}

extern "C" void kernel_launch(void* const* d_in, const int* in_sizes, int n_in,
                              void* d_out, int out_size, void* d_ws, size_t ws_size,
                              hipStream_t stream)
{
    const int* nodes_v = (const int*)d_in[0];
    const int* neigh_u = (const int*)d_in[1];
    const int* neigh_r = (const int*)d_in[2];
    const float* embed_u = (const float*)d_in[3];
    const float* embed_i = (const float*)d_in[4];
    const float* embed_r = (const float*)d_in[5];
    const float* gv_w1  = (const float*)d_in[6];  const float* gv_b1 = (const float*)d_in[7];
    const float* gv_w2  = (const float*)d_in[8];  const float* gv_b2 = (const float*)d_in[9];
    const float* gv_w3  = (const float*)d_in[10]; const float* gv_b3 = (const float*)d_in[11];
    const float* att_w1 = (const float*)d_in[12]; const float* att_b1 = (const float*)d_in[13];
    const float* att_w2 = (const float*)d_in[14]; const float* att_b2 = (const float*)d_in[15];
    const float* att_w3 = (const float*)d_in[16]; const float* att_b3 = (const float*)d_in[17];
    const float* wr1_w  = (const float*)d_in[18]; const float* wr1_b = (const float*)d_in[19];
    const float* wr2_w  = (const float*)d_in[20]; const float* wr2_b = (const float*)d_in[21];

    bf16* wt      = (bf16*)d_ws;
    float* bias1p = (float*)((char*)d_ws + BIAS1P_BYTE);
    bf16* zq      = (bf16*)((char*)d_ws + ZQ_BYTE);

    prep_weights<<<(WT_TOTAL + 64 + 255) / 256, 256, 0, stream>>>(
        gv_w1, gv_w2, gv_w3, att_w1, att_w2, wr1_w, wr2_w, gv_b3, att_b1, wt, bias1p);
    item_main<<<B_, 256, 0, stream>>>(nodes_v, neigh_u, neigh_r, embed_u, embed_i, embed_r,
                                      gv_b1, gv_b2, gv_b3, att_b2, att_w3, att_b3,
                                      wt, bias1p, zq);
    combine<<<B_ / 64, 256, 0, stream>>>(zq, wt, wr1_b, wr2_b, (float*)d_out);
}